// Round 6
// baseline (1123.630 us; speedup 1.0000x reference)
//
#include <hip/hip_runtime.h>
#include <stdint.h>
#include <stddef.h>

// ---------------------------------------------------------------------------
// AddInterpolant: xt/dt_xt of a 4-layer MLP flow interpolant, B=65536.
//   z=[x0|x1|t] (513)->1024->1024->1024->256, relu between; JVP wrt t-slot.
//   Tangent into layer1 is r1 = W1[512,:] (sample-independent).
//
// History:
//  R3: 128^2 2-barrier fused kernel + XCD swizzle: 1107us (mid 174us, 33%).
//  R4: coarse 4-quadrant phase split, redundant reads: 196us/29% (m196's
//      "coarse split without fine interleave hurts" signature).
//  R5: 2-phase counted-vmcnt 256^2: 1096us (mid 167us / 822TF / 34.6%).
//      LDS 128KB -> 1 block/CU -> 2 waves/SIMD: barrier+lgkm stalls unhidden.
//  R6: faithful 8-phase-class schedule at k-half (BK=32) granularity:
//      * LDS = 4 cycling 32KB sub-buffers (A 256x32 | B 256x32 each).
//      * per k-half q: 2 phases {4-8 ds_read_b128; 2 global_load_lds of
//        k-half q+3; sched_fence; barrier; lgkmcnt(0); setprio(1); 16 MFMA;
//        setprio(0); fence; barrier}. Staging 3 halves ahead, vmcnt(6)
//        steady (tail 4/0), never 0 mid-loop.
//      * buffer hazard proof: buf (q+3)&3 last read at phases of q-1; those
//        reads drained by lgkmcnt(0) before q-1B's trailing barrier; stage
//        is issued after that barrier. sched_barrier(0) pins phase edges.
//      * swizzle re-derived for 32-col rows: storage slot = hi^(row&3);
//        worst 2-way bank aliasing (free, m136).
// ---------------------------------------------------------------------------

typedef unsigned short u16;
typedef __attribute__((ext_vector_type(8))) short short8;
typedef __attribute__((ext_vector_type(4))) float f32x4;

#define BATCH 65536
#define SDIM 256
#define HDIM 1024

__device__ __forceinline__ u16 f2bf(float f) {
  unsigned int u = __float_as_uint(f);
  u += 0x7FFFu + ((u >> 16) & 1u);   // round-to-nearest-even
  return (u16)(u >> 16);
}

__device__ __forceinline__ void gload_lds16(const void* g, void* l) {
  // 16B/lane; LDS dest = wave-uniform base + lane*16 (hardware rule).
  __builtin_amdgcn_global_load_lds(
      (const __attribute__((address_space(1))) unsigned int*)g,
      (__attribute__((address_space(3))) unsigned int*)l, 16, 0, 0);
}

struct EpiArgs {
  const float* bias;
  const float* r1;    // W1 row 512 (f32)
  const float* t;     // chunk-local base
  const float* x0;
  const float* x1;
  u16*   out_h;       // stacked S output (EPI 0/1)
  float* out_xt;
  float* out_dt;
};

// C = A[M,K] @ Bt[N,K]^T, bf16 in, f32 acc. BM=BN=256, K in 32-wide halves.
// 512 threads = 8 waves (2M x 4N); per-wave C = 128x64 = acc[8][4] f32x4.
// EPI 0: layer1 (A=Z, K=512): pre=acc+b[n]+t[m]*r1[n]; stacked H/U out.
// EPI 1: mid (A=S stacked): even/odd 32-row pairs -> relu H', masked U'.
// EPI 2: layer4+combine -> xt, dt_xt (f32).
template <int EPI>
__global__ __launch_bounds__(512, 2)
void fgemm8(const u16* __restrict__ A, const u16* __restrict__ Bt,
            int N, int K, EpiArgs e)
{
  // 4 sub-buffers x 16384 u16 (A 8192 | B 8192) = 128 KiB.
  __shared__ __align__(16) u16 lds[65536];

  const int tid  = threadIdx.x;
  const int wave = tid >> 6;
  const int lane = tid & 63;
  const int hi   = lane >> 4;   // 0..3 (k-chunk of the MFMA fragment)
  const int ln   = lane & 15;

  // Staging geometry: thread covers 16B = 8 cols of one row per load.
  const int srow4  = tid >> 2;                    // 0..127 (row within half)
  const int schunk = (tid & 3) ^ (srow4 & 3);     // global-side swizzled slot

  // Band-preserving XCD swizzle (verified R3: FETCH 528->105MB, WRITE ideal).
  const int nbx = gridDim.x;
  int bx = blockIdx.x, by = blockIdx.y;
  if ((gridDim.y & 7) == 0) {
    const int id = by * nbx + bx;
    const int g  = id & 7;
    const int s  = id >> 3;
    bx = s % nbx;
    by = (s / nbx) * 8 + g;
  }
  const int bn = bx * 256;
  const int bm = by * 256;

  const int wm = (wave >> 2) * 128;   // 2 M-wave groups
  const int wn = (wave & 3) * 64;     // 4 N-wave groups

  f32x4 acc[8][4] = {};

  const int NH = K >> 5;              // k-halves (16 or 32)

  // Per-thread global staging bases (strength-reduced: +q*32 per half).
  const u16* pA = A  + (size_t)(bm + srow4) * K + schunk * 8;
  const u16* pB = Bt + (size_t)(bn + srow4) * K + schunk * 8;
  const size_t rstep = (size_t)128 * K;

  // Stage piece: 0 = A-half of k-half q (2 loads), 1 = B-half.
  auto STAGE = [&](int q, int piece) {
    const int base = ((q & 3) << 14) + (piece << 13) + tid * 8;
    const u16* gp  = (piece ? pB : pA) + q * 32;
#pragma unroll
    for (int r = 0; r < 2; ++r)
      gload_lds16(gp + r * rstep, &lds[base + r * 4096]);
  };

  // LDS read offsets (u16): row*32 + (hi^(row&3))*8; row&3 == ln&3.
  const int slot = (hi ^ (ln & 3)) << 3;
  int aoff[8], boff[4];
#pragma unroll
  for (int i = 0; i < 8; ++i) aoff[i] = (wm + i * 16 + ln) * 32 + slot;
#pragma unroll
  for (int j = 0; j < 4; ++j) boff[j] = 8192 + (wn + j * 16 + ln) * 32 + slot;

  // Prologue: k-halves 0,1,2 (12 loads); prove half 0 (retire oldest 4).
  STAGE(0, 0); STAGE(0, 1);
  STAGE(1, 0); STAGE(1, 1);
  STAGE(2, 0); STAGE(2, 1);
  asm volatile("s_waitcnt vmcnt(8)" ::: "memory");
  __builtin_amdgcn_s_barrier();

  for (int q = 0; q < NH; ++q) {
    const int buf = (q & 3) << 14;

    // ---- phase A (m-half 0): 8 reads + stage A(q+3) + 16 MFMA ----
    short8 a0[4], b0[4];
#pragma unroll
    for (int i = 0; i < 4; ++i) a0[i] = *(const short8*)&lds[buf + aoff[i]];
#pragma unroll
    for (int j = 0; j < 4; ++j) b0[j] = *(const short8*)&lds[buf + boff[j]];
    if (q + 3 < NH) STAGE(q + 3, 0);
    __builtin_amdgcn_sched_barrier(0);
    __builtin_amdgcn_s_barrier();
    asm volatile("s_waitcnt lgkmcnt(0)" ::: "memory");
    __builtin_amdgcn_sched_barrier(0);
    __builtin_amdgcn_s_setprio(1);
#pragma unroll
    for (int i = 0; i < 4; ++i)
#pragma unroll
      for (int j = 0; j < 4; ++j)
        acc[i][j] = __builtin_amdgcn_mfma_f32_16x16x32_bf16(
            a0[i], b0[j], acc[i][j], 0, 0, 0);
    __builtin_amdgcn_s_setprio(0);
    __builtin_amdgcn_sched_barrier(0);
    __builtin_amdgcn_s_barrier();

    // ---- phase B (m-half 1): 4 reads + vmcnt + stage B(q+3) + 16 MFMA ----
    short8 a1[4];
#pragma unroll
    for (int i = 0; i < 4; ++i) a1[i] = *(const short8*)&lds[buf + aoff[4 + i]];
    // Prove k-half q+1 landed (consumed next phase-pair). Steady: 6 in
    // flight (q+2's 4 + A(q+3)'s 2). Tail peels to 4 / 0.
    if (q + 1 < NH) {
      if (q < NH - 3)       asm volatile("s_waitcnt vmcnt(6)" ::: "memory");
      else if (q == NH - 3) asm volatile("s_waitcnt vmcnt(4)" ::: "memory");
      else                  asm volatile("s_waitcnt vmcnt(0)" ::: "memory");
    }
    if (q + 3 < NH) STAGE(q + 3, 1);
    __builtin_amdgcn_sched_barrier(0);
    __builtin_amdgcn_s_barrier();
    asm volatile("s_waitcnt lgkmcnt(0)" ::: "memory");
    __builtin_amdgcn_sched_barrier(0);
    __builtin_amdgcn_s_setprio(1);
#pragma unroll
    for (int i = 0; i < 4; ++i)
#pragma unroll
      for (int j = 0; j < 4; ++j)
        acc[4 + i][j] = __builtin_amdgcn_mfma_f32_16x16x32_bf16(
            a1[i], b0[j], acc[4 + i][j], 0, 0, 0);
    __builtin_amdgcn_s_setprio(0);
    __builtin_amdgcn_sched_barrier(0);
    __builtin_amdgcn_s_barrier();
  }

  // ---- epilogue. C/D layout: col = lane&15, row = (lane>>4)*4 + reg [m89].
  if constexpr (EPI == 0) {
    // A rows were samples. Write stacked: H -> row sH, U=mask*r1 -> sH+16.
#pragma unroll
    for (int mi = 0; mi < 8; ++mi) {
#pragma unroll
      for (int ni = 0; ni < 4; ++ni) {
        const int n = bn + wn + ni * 16 + ln;
        const float bnv = e.bias[n];
        const float r1n = e.r1[n];
#pragma unroll
        for (int r = 0; r < 4; ++r) {
          const int m = bm + wm + mi * 16 + hi * 4 + r;   // chunk-local sample
          const float pre = acc[mi][ni][r] + bnv + e.t[m] * r1n;
          const size_t sH = (size_t)(m >> 4) * 32 + (m & 15);
          e.out_h[sH * (size_t)N + n]        = f2bf(fmaxf(pre, 0.f));
          e.out_h[(sH + 16) * (size_t)N + n] = (pre > 0.f) ? f2bf(r1n) : (u16)0;
        }
      }
    }
  } else if constexpr (EPI == 1) {
    // Stacked in, stacked out: mi pairs (2j=H, 2j+1=U) of same samples.
#pragma unroll
    for (int j = 0; j < 4; ++j) {
#pragma unroll
      for (int ni = 0; ni < 4; ++ni) {
        const int n = bn + wn + ni * 16 + ln;
        const float bnv = e.bias[n];
#pragma unroll
        for (int r = 0; r < 4; ++r) {
          const size_t sH = (size_t)(bm + wm + j * 32 + hi * 4 + r);
          const float pre = acc[2 * j][ni][r] + bnv;
          const float vu  = acc[2 * j + 1][ni][r];
          e.out_h[sH * (size_t)N + n]        = f2bf(fmaxf(pre, 0.f));
          e.out_h[(sH + 16) * (size_t)N + n] = (pre > 0.f) ? f2bf(vu) : (u16)0;
        }
      }
    }
  } else {
    // Final: fnn (even mi) + dtfnn (odd mi) -> xt, dt_xt.
#pragma unroll
    for (int j = 0; j < 4; ++j) {
#pragma unroll
      for (int ni = 0; ni < 4; ++ni) {
        const int n = bn + wn + ni * 16 + ln;   // < 256
        const float bnv = e.bias[n];
#pragma unroll
        for (int r = 0; r < 4; ++r) {
          const int sH = bm + wm + j * 32 + hi * 4 + r;
          const int m  = ((sH >> 5) << 4) + (hi * 4 + r);  // chunk-local sample
          const float fnn = acc[2 * j][ni][r] + bnv;
          const float dtf = acc[2 * j + 1][ni][r];
          const float tt  = e.t[m];
          const size_t ix = (size_t)m * 256 + n;
          const float a = e.x0[ix], b = e.x1[ix];
          const float w = tt * (1.f - tt);
          e.out_xt[ix] = (1.f - tt) * a + tt * b + w * fnn;
          e.out_dt[ix] = b - a + (1.f - 2.f * tt) * fnn + w * dtf;
        }
      }
    }
  }
}

// Z = bf16([x0 | x1]) chunk, [CB, 512]; one thread per 4 elements.
__global__ void prep_z(const float* __restrict__ x0, const float* __restrict__ x1,
                       u16* __restrict__ A0)
{
  const int idx = blockIdx.x * blockDim.x + threadIdx.x;
  const int m = idx >> 7;        // 128 4-elem chunks per row
  const int c = idx & 127;
  const float* src = (c < 64) ? (x0 + (size_t)m * 256 + c * 4)
                              : (x1 + (size_t)m * 256 + (c - 64) * 4);
  const float4 v = *(const float4*)src;
  uint2 pk;
  pk.x = (unsigned)f2bf(v.x) | ((unsigned)f2bf(v.y) << 16);
  pk.y = (unsigned)f2bf(v.z) | ((unsigned)f2bf(v.w) << 16);
  *(uint2*)&A0[(size_t)m * 512 + c * 4] = pk;
}

// Wt[N,K] bf16 <- W[K,N] f32, 32x32 LDS tile transpose.
__global__ void transpose_cast(const float* __restrict__ W, u16* __restrict__ Wt,
                               int K, int N)
{
  __shared__ float tile[32][33];
  const int tx = threadIdx.x & 31;
  const int ty = threadIdx.x >> 5;  // 0..7
  const int k0 = blockIdx.x * 32;
  const int n0 = blockIdx.y * 32;
#pragma unroll
  for (int i = 0; i < 32; i += 8)
    tile[ty + i][tx] = W[(size_t)(k0 + ty + i) * N + n0 + tx];
  __syncthreads();
#pragma unroll
  for (int i = 0; i < 32; i += 8)
    Wt[(size_t)(n0 + ty + i) * K + k0 + tx] = f2bf(tile[tx][ty + i]);
}

extern "C" void kernel_launch(void* const* d_in, const int* in_sizes, int n_in,
                              void* d_out, int out_size, void* d_ws, size_t ws_size,
                              hipStream_t stream)
{
  const float* x0 = (const float*)d_in[0];
  const float* x1 = (const float*)d_in[1];
  const float* t  = (const float*)d_in[2];
  const float* W1 = (const float*)d_in[3];
  const float* b1 = (const float*)d_in[4];
  const float* W2 = (const float*)d_in[5];
  const float* b2 = (const float*)d_in[6];
  const float* W3 = (const float*)d_in[7];
  const float* b3 = (const float*)d_in[8];
  const float* W4 = (const float*)d_in[9];
  const float* b4 = (const float*)d_in[10];

  char* ws = (char*)d_ws;
  const size_t WB1 = (size_t)512 * HDIM * 2;   // 1 MiB
  const size_t WB2 = (size_t)HDIM * HDIM * 2;  // 2 MiB
  const size_t WB4 = (size_t)HDIM * SDIM * 2;  // 0.5 MiB
  u16* Wt1 = (u16*)(ws);
  u16* Wt2 = (u16*)(ws + WB1);
  u16* Wt3 = (u16*)(ws + WB1 + WB2);
  u16* Wt4 = (u16*)(ws + WB1 + 2 * WB2);
  const size_t wmark = WB1 + 2 * WB2 + WB4;    // 5.5 MiB
  char* act = ws + wmark;

  // Stacked activations: Sa, Sb = [2*CB, 1024] bf16 = CB*4096 B each.
  int nc = 1;
  while (nc < 64 && wmark + (size_t)(BATCH / nc) * 8192 > ws_size) nc <<= 1;
  const int CB = BATCH / nc;

  u16* Sa = (u16*)(act);
  u16* Sb = (u16*)(act + (size_t)CB * 4096);
  u16* Zc = Sb;  // alias: Z chunk (CB*1024 B) dead once layer 2 writes Sb

  transpose_cast<<<dim3(16, 32), 256, 0, stream>>>(W1, Wt1, 512, HDIM);
  transpose_cast<<<dim3(32, 32), 256, 0, stream>>>(W2, Wt2, HDIM, HDIM);
  transpose_cast<<<dim3(32, 32), 256, 0, stream>>>(W3, Wt3, HDIM, HDIM);
  transpose_cast<<<dim3(32, 8),  256, 0, stream>>>(W4, Wt4, HDIM, SDIM);

  const float* r1 = W1 + (size_t)512 * HDIM;   // last row of W1
  float* out_xt = (float*)d_out;
  float* out_dt = (float*)d_out + (size_t)BATCH * SDIM;

  for (int c = 0; c < nc; ++c) {
    const size_t mb = (size_t)c * CB;

    prep_z<<<(CB * 128) / 256, 256, 0, stream>>>(x0 + mb * SDIM, x1 + mb * SDIM, Zc);

    { EpiArgs e{}; e.bias = b1; e.r1 = r1; e.t = t + mb; e.out_h = Sa;
      fgemm8<0><<<dim3(HDIM / 256, CB / 256), 512, 0, stream>>>(Zc, Wt1, HDIM, 512, e); }

    { EpiArgs e{}; e.bias = b2; e.out_h = Sb;
      fgemm8<1><<<dim3(HDIM / 256, CB / 128), 512, 0, stream>>>(Sa, Wt2, HDIM, HDIM, e); }

    { EpiArgs e{}; e.bias = b3; e.out_h = Sa;
      fgemm8<1><<<dim3(HDIM / 256, CB / 128), 512, 0, stream>>>(Sb, Wt3, HDIM, HDIM, e); }

    { EpiArgs e{}; e.bias = b4; e.t = t + mb;
      e.x0 = x0 + mb * SDIM; e.x1 = x1 + mb * SDIM;
      e.out_xt = out_xt + mb * SDIM; e.out_dt = out_dt + mb * SDIM;
      fgemm8<2><<<dim3(SDIM / 256, CB / 128), 512, 0, stream>>>(Sa, Wt4, SDIM, HDIM, e); }
  }
}

// Round 7
// 1095.046 us; speedup vs baseline: 1.0261x; 1.0261x over previous
//
#include <hip/hip_runtime.h>
#include <stdint.h>
#include <stddef.h>

// ---------------------------------------------------------------------------
// AddInterpolant: xt/dt_xt of a 4-layer MLP flow interpolant, B=65536.
//   z=[x0|x1|t] (513)->1024->1024->1024->256, relu between; JVP wrt t-slot.
//   Tangent into layer1 is r1 = W1[512,:] (sample-independent).
//
// History:
//  R3: 128^2 2-barrier fused kernel + XCD swizzle: 1107us (mid 174us, 33%).
//  R5: 2-phase counted-vmcnt 256^2: 1096us (mid 167us / 822TF / 34.6%).
//  R6: k-half (BK=32) 8-phase-class schedule: REGRESSED (184us / 32.7%),
//      SQ_LDS_BANK_CONFLICT 1.26e7. Root cause: 64B rows put row-parity in
//      the bank index; slot=hi^(ln&3) left lanes {ln,ln+4,ln+8,ln+12} on one
//      4-bank group -> 4-way conflict (1.58x) on the phase critical path.
//  R7: swizzle fix only (A/B vs R6): f(row) = (row>>1)&3 on BOTH sides:
//      read slot = hi^((ln>>1)&3) -> (parity,slot) covers all 8 bank-groups,
//      2 lanes each = free; storage schunk = (tid&3)^((tid>>3)&3).
//      Everything else byte-identical to R6.
// ---------------------------------------------------------------------------

typedef unsigned short u16;
typedef __attribute__((ext_vector_type(8))) short short8;
typedef __attribute__((ext_vector_type(4))) float f32x4;

#define BATCH 65536
#define SDIM 256
#define HDIM 1024

__device__ __forceinline__ u16 f2bf(float f) {
  unsigned int u = __float_as_uint(f);
  u += 0x7FFFu + ((u >> 16) & 1u);   // round-to-nearest-even
  return (u16)(u >> 16);
}

__device__ __forceinline__ void gload_lds16(const void* g, void* l) {
  // 16B/lane; LDS dest = wave-uniform base + lane*16 (hardware rule).
  __builtin_amdgcn_global_load_lds(
      (const __attribute__((address_space(1))) unsigned int*)g,
      (__attribute__((address_space(3))) unsigned int*)l, 16, 0, 0);
}

struct EpiArgs {
  const float* bias;
  const float* r1;    // W1 row 512 (f32)
  const float* t;     // chunk-local base
  const float* x0;
  const float* x1;
  u16*   out_h;       // stacked S output (EPI 0/1)
  float* out_xt;
  float* out_dt;
};

// C = A[M,K] @ Bt[N,K]^T, bf16 in, f32 acc. BM=BN=256, K in 32-wide halves.
// 512 threads = 8 waves (2M x 4N); per-wave C = 128x64 = acc[8][4] f32x4.
// EPI 0: layer1 (A=Z, K=512): pre=acc+b[n]+t[m]*r1[n]; stacked H/U out.
// EPI 1: mid (A=S stacked): even/odd 32-row pairs -> relu H', masked U'.
// EPI 2: layer4+combine -> xt, dt_xt (f32).
template <int EPI>
__global__ __launch_bounds__(512, 2)
void fgemm8(const u16* __restrict__ A, const u16* __restrict__ Bt,
            int N, int K, EpiArgs e)
{
  // 4 sub-buffers x 16384 u16 (A 8192 | B 8192) = 128 KiB.
  __shared__ __align__(16) u16 lds[65536];

  const int tid  = threadIdx.x;
  const int wave = tid >> 6;
  const int lane = tid & 63;
  const int hi   = lane >> 4;   // 0..3 (k-chunk of the MFMA fragment)
  const int ln   = lane & 15;

  // Staging geometry: thread covers 16B = 8 cols of one row per load.
  // R7 swizzle: slot = chunk ^ f(row), f(row) = (row>>1)&3.
  const int srow4  = tid >> 2;                    // 0..127 (row within piece)
  const int schunk = (tid & 3) ^ ((tid >> 3) & 3);  // swizzled storage slot

  // Band-preserving XCD swizzle (verified R3: FETCH 528->105MB, WRITE ideal).
  const int nbx = gridDim.x;
  int bx = blockIdx.x, by = blockIdx.y;
  if ((gridDim.y & 7) == 0) {
    const int id = by * nbx + bx;
    const int g  = id & 7;
    const int s  = id >> 3;
    bx = s % nbx;
    by = (s / nbx) * 8 + g;
  }
  const int bn = bx * 256;
  const int bm = by * 256;

  const int wm = (wave >> 2) * 128;   // 2 M-wave groups
  const int wn = (wave & 3) * 64;     // 4 N-wave groups

  f32x4 acc[8][4] = {};

  const int NH = K >> 5;              // k-halves (16 or 32)

  // Per-thread global staging bases (strength-reduced: +q*32 per half).
  const u16* pA = A  + (size_t)(bm + srow4) * K + schunk * 8;
  const u16* pB = Bt + (size_t)(bn + srow4) * K + schunk * 8;
  const size_t rstep = (size_t)128 * K;

  // Stage piece: 0 = A-half of k-half q (2 loads), 1 = B-half.
  auto STAGE = [&](int q, int piece) {
    const int base = ((q & 3) << 14) + (piece << 13) + tid * 8;
    const u16* gp  = (piece ? pB : pA) + q * 32;
#pragma unroll
    for (int r = 0; r < 2; ++r)
      gload_lds16(gp + r * rstep, &lds[base + r * 4096]);
  };

  // LDS read offsets (u16): row*32 + (hi^((row>>1)&3))*8; (row>>1)&3 ==
  // (ln>>1)&3 since row = 16k + ln. Bank: 16*(ln&1) + 4*slot -> the 16-lane
  // phase covers all 8 bank-groups with 2 lanes each (2-way = free, m136).
  const int slot = (hi ^ ((ln >> 1) & 3)) << 3;
  int aoff[8], boff[4];
#pragma unroll
  for (int i = 0; i < 8; ++i) aoff[i] = (wm + i * 16 + ln) * 32 + slot;
#pragma unroll
  for (int j = 0; j < 4; ++j) boff[j] = 8192 + (wn + j * 16 + ln) * 32 + slot;

  // Prologue: k-halves 0,1,2 (12 loads); prove half 0 (retire oldest 4).
  STAGE(0, 0); STAGE(0, 1);
  STAGE(1, 0); STAGE(1, 1);
  STAGE(2, 0); STAGE(2, 1);
  asm volatile("s_waitcnt vmcnt(8)" ::: "memory");
  __builtin_amdgcn_s_barrier();

  for (int q = 0; q < NH; ++q) {
    const int buf = (q & 3) << 14;

    // ---- phase A (m-half 0): 8 reads + stage A(q+3) + 16 MFMA ----
    short8 a0[4], b0[4];
#pragma unroll
    for (int i = 0; i < 4; ++i) a0[i] = *(const short8*)&lds[buf + aoff[i]];
#pragma unroll
    for (int j = 0; j < 4; ++j) b0[j] = *(const short8*)&lds[buf + boff[j]];
    if (q + 3 < NH) STAGE(q + 3, 0);
    __builtin_amdgcn_sched_barrier(0);
    __builtin_amdgcn_s_barrier();
    asm volatile("s_waitcnt lgkmcnt(0)" ::: "memory");
    __builtin_amdgcn_sched_barrier(0);
    __builtin_amdgcn_s_setprio(1);
#pragma unroll
    for (int i = 0; i < 4; ++i)
#pragma unroll
      for (int j = 0; j < 4; ++j)
        acc[i][j] = __builtin_amdgcn_mfma_f32_16x16x32_bf16(
            a0[i], b0[j], acc[i][j], 0, 0, 0);
    __builtin_amdgcn_s_setprio(0);
    __builtin_amdgcn_sched_barrier(0);
    __builtin_amdgcn_s_barrier();

    // ---- phase B (m-half 1): 4 reads + vmcnt + stage B(q+3) + 16 MFMA ----
    short8 a1[4];
#pragma unroll
    for (int i = 0; i < 4; ++i) a1[i] = *(const short8*)&lds[buf + aoff[4 + i]];
    // Prove k-half q+1 landed (consumed next phase-pair). Steady: 6 in
    // flight (q+2's 4 + A(q+3)'s 2). Tail peels to 4 / 0.
    if (q + 1 < NH) {
      if (q < NH - 3)       asm volatile("s_waitcnt vmcnt(6)" ::: "memory");
      else if (q == NH - 3) asm volatile("s_waitcnt vmcnt(4)" ::: "memory");
      else                  asm volatile("s_waitcnt vmcnt(0)" ::: "memory");
    }
    if (q + 3 < NH) STAGE(q + 3, 1);
    __builtin_amdgcn_sched_barrier(0);
    __builtin_amdgcn_s_barrier();
    asm volatile("s_waitcnt lgkmcnt(0)" ::: "memory");
    __builtin_amdgcn_sched_barrier(0);
    __builtin_amdgcn_s_setprio(1);
#pragma unroll
    for (int i = 0; i < 4; ++i)
#pragma unroll
      for (int j = 0; j < 4; ++j)
        acc[4 + i][j] = __builtin_amdgcn_mfma_f32_16x16x32_bf16(
            a1[i], b0[j], acc[4 + i][j], 0, 0, 0);
    __builtin_amdgcn_s_setprio(0);
    __builtin_amdgcn_sched_barrier(0);
    __builtin_amdgcn_s_barrier();
  }

  // ---- epilogue. C/D layout: col = lane&15, row = (lane>>4)*4 + reg [m89].
  if constexpr (EPI == 0) {
    // A rows were samples. Write stacked: H -> row sH, U=mask*r1 -> sH+16.
#pragma unroll
    for (int mi = 0; mi < 8; ++mi) {
#pragma unroll
      for (int ni = 0; ni < 4; ++ni) {
        const int n = bn + wn + ni * 16 + ln;
        const float bnv = e.bias[n];
        const float r1n = e.r1[n];
#pragma unroll
        for (int r = 0; r < 4; ++r) {
          const int m = bm + wm + mi * 16 + hi * 4 + r;   // chunk-local sample
          const float pre = acc[mi][ni][r] + bnv + e.t[m] * r1n;
          const size_t sH = (size_t)(m >> 4) * 32 + (m & 15);
          e.out_h[sH * (size_t)N + n]        = f2bf(fmaxf(pre, 0.f));
          e.out_h[(sH + 16) * (size_t)N + n] = (pre > 0.f) ? f2bf(r1n) : (u16)0;
        }
      }
    }
  } else if constexpr (EPI == 1) {
    // Stacked in, stacked out: mi pairs (2j=H, 2j+1=U) of same samples.
#pragma unroll
    for (int j = 0; j < 4; ++j) {
#pragma unroll
      for (int ni = 0; ni < 4; ++ni) {
        const int n = bn + wn + ni * 16 + ln;
        const float bnv = e.bias[n];
#pragma unroll
        for (int r = 0; r < 4; ++r) {
          const size_t sH = (size_t)(bm + wm + j * 32 + hi * 4 + r);
          const float pre = acc[2 * j][ni][r] + bnv;
          const float vu  = acc[2 * j + 1][ni][r];
          e.out_h[sH * (size_t)N + n]        = f2bf(fmaxf(pre, 0.f));
          e.out_h[(sH + 16) * (size_t)N + n] = (pre > 0.f) ? f2bf(vu) : (u16)0;
        }
      }
    }
  } else {
    // Final: fnn (even mi) + dtfnn (odd mi) -> xt, dt_xt.
#pragma unroll
    for (int j = 0; j < 4; ++j) {
#pragma unroll
      for (int ni = 0; ni < 4; ++ni) {
        const int n = bn + wn + ni * 16 + ln;   // < 256
        const float bnv = e.bias[n];
#pragma unroll
        for (int r = 0; r < 4; ++r) {
          const int sH = bm + wm + j * 32 + hi * 4 + r;
          const int m  = ((sH >> 5) << 4) + (hi * 4 + r);  // chunk-local sample
          const float fnn = acc[2 * j][ni][r] + bnv;
          const float dtf = acc[2 * j + 1][ni][r];
          const float tt  = e.t[m];
          const size_t ix = (size_t)m * 256 + n;
          const float a = e.x0[ix], b = e.x1[ix];
          const float w = tt * (1.f - tt);
          e.out_xt[ix] = (1.f - tt) * a + tt * b + w * fnn;
          e.out_dt[ix] = b - a + (1.f - 2.f * tt) * fnn + w * dtf;
        }
      }
    }
  }
}

// Z = bf16([x0 | x1]) chunk, [CB, 512]; one thread per 4 elements.
__global__ void prep_z(const float* __restrict__ x0, const float* __restrict__ x1,
                       u16* __restrict__ A0)
{
  const int idx = blockIdx.x * blockDim.x + threadIdx.x;
  const int m = idx >> 7;        // 128 4-elem chunks per row
  const int c = idx & 127;
  const float* src = (c < 64) ? (x0 + (size_t)m * 256 + c * 4)
                              : (x1 + (size_t)m * 256 + (c - 64) * 4);
  const float4 v = *(const float4*)src;
  uint2 pk;
  pk.x = (unsigned)f2bf(v.x) | ((unsigned)f2bf(v.y) << 16);
  pk.y = (unsigned)f2bf(v.z) | ((unsigned)f2bf(v.w) << 16);
  *(uint2*)&A0[(size_t)m * 512 + c * 4] = pk;
}

// Wt[N,K] bf16 <- W[K,N] f32, 32x32 LDS tile transpose.
__global__ void transpose_cast(const float* __restrict__ W, u16* __restrict__ Wt,
                               int K, int N)
{
  __shared__ float tile[32][33];
  const int tx = threadIdx.x & 31;
  const int ty = threadIdx.x >> 5;  // 0..7
  const int k0 = blockIdx.x * 32;
  const int n0 = blockIdx.y * 32;
#pragma unroll
  for (int i = 0; i < 32; i += 8)
    tile[ty + i][tx] = W[(size_t)(k0 + ty + i) * N + n0 + tx];
  __syncthreads();
#pragma unroll
  for (int i = 0; i < 32; i += 8)
    Wt[(size_t)(n0 + ty + i) * K + k0 + tx] = f2bf(tile[tx][ty + i]);
}

extern "C" void kernel_launch(void* const* d_in, const int* in_sizes, int n_in,
                              void* d_out, int out_size, void* d_ws, size_t ws_size,
                              hipStream_t stream)
{
  const float* x0 = (const float*)d_in[0];
  const float* x1 = (const float*)d_in[1];
  const float* t  = (const float*)d_in[2];
  const float* W1 = (const float*)d_in[3];
  const float* b1 = (const float*)d_in[4];
  const float* W2 = (const float*)d_in[5];
  const float* b2 = (const float*)d_in[6];
  const float* W3 = (const float*)d_in[7];
  const float* b3 = (const float*)d_in[8];
  const float* W4 = (const float*)d_in[9];
  const float* b4 = (const float*)d_in[10];

  char* ws = (char*)d_ws;
  const size_t WB1 = (size_t)512 * HDIM * 2;   // 1 MiB
  const size_t WB2 = (size_t)HDIM * HDIM * 2;  // 2 MiB
  const size_t WB4 = (size_t)HDIM * SDIM * 2;  // 0.5 MiB
  u16* Wt1 = (u16*)(ws);
  u16* Wt2 = (u16*)(ws + WB1);
  u16* Wt3 = (u16*)(ws + WB1 + WB2);
  u16* Wt4 = (u16*)(ws + WB1 + 2 * WB2);
  const size_t wmark = WB1 + 2 * WB2 + WB4;    // 5.5 MiB
  char* act = ws + wmark;

  // Stacked activations: Sa, Sb = [2*CB, 1024] bf16 = CB*4096 B each.
  int nc = 1;
  while (nc < 64 && wmark + (size_t)(BATCH / nc) * 8192 > ws_size) nc <<= 1;
  const int CB = BATCH / nc;

  u16* Sa = (u16*)(act);
  u16* Sb = (u16*)(act + (size_t)CB * 4096);
  u16* Zc = Sb;  // alias: Z chunk (CB*1024 B) dead once layer 2 writes Sb

  transpose_cast<<<dim3(16, 32), 256, 0, stream>>>(W1, Wt1, 512, HDIM);
  transpose_cast<<<dim3(32, 32), 256, 0, stream>>>(W2, Wt2, HDIM, HDIM);
  transpose_cast<<<dim3(32, 32), 256, 0, stream>>>(W3, Wt3, HDIM, HDIM);
  transpose_cast<<<dim3(32, 8),  256, 0, stream>>>(W4, Wt4, HDIM, SDIM);

  const float* r1 = W1 + (size_t)512 * HDIM;   // last row of W1
  float* out_xt = (float*)d_out;
  float* out_dt = (float*)d_out + (size_t)BATCH * SDIM;

  for (int c = 0; c < nc; ++c) {
    const size_t mb = (size_t)c * CB;

    prep_z<<<(CB * 128) / 256, 256, 0, stream>>>(x0 + mb * SDIM, x1 + mb * SDIM, Zc);

    { EpiArgs e{}; e.bias = b1; e.r1 = r1; e.t = t + mb; e.out_h = Sa;
      fgemm8<0><<<dim3(HDIM / 256, CB / 256), 512, 0, stream>>>(Zc, Wt1, HDIM, 512, e); }

    { EpiArgs e{}; e.bias = b2; e.out_h = Sb;
      fgemm8<1><<<dim3(HDIM / 256, CB / 128), 512, 0, stream>>>(Sa, Wt2, HDIM, HDIM, e); }

    { EpiArgs e{}; e.bias = b3; e.out_h = Sa;
      fgemm8<1><<<dim3(HDIM / 256, CB / 128), 512, 0, stream>>>(Sb, Wt3, HDIM, HDIM, e); }

    { EpiArgs e{}; e.bias = b4; e.t = t + mb;
      e.x0 = x0 + mb * SDIM; e.x1 = x1 + mb * SDIM;
      e.out_xt = out_xt + mb * SDIM; e.out_dt = out_dt + mb * SDIM;
      fgemm8<2><<<dim3(SDIM / 256, CB / 128), 512, 0, stream>>>(Sa, Wt4, SDIM, HDIM, e); }
  }
}